// Round 4
// baseline (834.404 us; speedup 1.0000x reference)
//
#include <hip/hip_runtime.h>
#include <stdint.h>

// ---------------------------------------------------------------------------
// HistoryEmbTable: emb.at[push_idx].set(x) then gather emb[pull_idx].
// Last push (highest i) wins on duplicate push indices.
//
// Round-3 insight: ANY global hash/bitmap touched by 4M single-element random
// accesses costs ~50-90us/pass in 64B-line traffic; we had three such passes
// plus the pull. Replace with bucket partitioning (bucket = key>>16, 1024
// buckets of 64K keys = 256KB emb slice each):
//   hist -> scan -> scatter(push pairs, pull keys) -> per-bucket LDS-hash
//   match+gather (emb slice L2-resident, writes coalesced) -> unpermute.
// Everything is streaming except emb lines (deduped, XCD-local) and 16MB-
// footprint cached gathers (x, staging).
// ---------------------------------------------------------------------------

#define NB      1024            // buckets
#define BSHIFT  16              // key>>16 -> bucket (keys < 2^26)
#define PAD     16              // ints per counter slot (64B anti-contention)
#define LSLOTS  8192            // LDS hash slots per bucket (64KB)
#define LMASK   (LSLOTS - 1)
#define HIST_ELEMS 16

__global__ void hist_kernel(const int* __restrict__ push_idx,
                            const int* __restrict__ pull_idx,
                            int n_push, int n_pull,
                            int* __restrict__ cnt_push,
                            int* __restrict__ cnt_pull) {
    __shared__ int hA[NB], hB[NB];
    for (int t = threadIdx.x; t < NB; t += blockDim.x) { hA[t] = 0; hB[t] = 0; }
    __syncthreads();
    int base = blockIdx.x * (blockDim.x * HIST_ELEMS);
    for (int e = 0; e < HIST_ELEMS; ++e) {
        int i = base + e * blockDim.x + threadIdx.x;
        if (i < n_push) atomicAdd(&hA[push_idx[i] >> BSHIFT], 1);
        if (i < n_pull) atomicAdd(&hB[pull_idx[i] >> BSHIFT], 1);
    }
    __syncthreads();
    for (int t = threadIdx.x; t < NB; t += blockDim.x) {
        if (hA[t]) atomicAdd(&cnt_push[t * PAD], hA[t]);
        if (hB[t]) atomicAdd(&cnt_pull[t * PAD], hB[t]);
    }
}

__global__ void scan_kernel(const int* __restrict__ cnt_push,
                            const int* __restrict__ cnt_pull,
                            int* __restrict__ off_push, int* __restrict__ off_pull,
                            int* __restrict__ cur_push, int* __restrict__ cur_pull) {
    __shared__ int sA[NB], sB[NB];
    int t = threadIdx.x;
    int cA = cnt_push[t * PAD];
    int cB = cnt_pull[t * PAD];
    sA[t] = cA; sB[t] = cB;
    __syncthreads();
    for (int d = 1; d < NB; d <<= 1) {
        int a = (t >= d) ? sA[t - d] : 0;
        int b = (t >= d) ? sB[t - d] : 0;
        __syncthreads();
        sA[t] += a; sB[t] += b;
        __syncthreads();
    }
    int oA = sA[t] - cA, oB = sB[t] - cB;   // exclusive
    off_push[t] = oA;          off_pull[t] = oB;
    cur_push[t * PAD] = oA;    cur_pull[t * PAD] = oB;
}

__global__ void scatter_push_kernel(const int* __restrict__ push_idx, int n,
                                    int* __restrict__ cur_push,
                                    unsigned long long* __restrict__ push_pairs) {
    int i = blockIdx.x * blockDim.x + threadIdx.x;
    if (i >= n) return;
    int key = push_idx[i];
    int b = key >> BSHIFT;
    int p = atomicAdd(&cur_push[b * PAD], 1);
    push_pairs[p] = ((unsigned long long)(unsigned)key << 32) | (unsigned)(i + 1);
}

__global__ void scatter_pull_kernel(const int* __restrict__ pull_idx, int n,
                                    int* __restrict__ cur_pull,
                                    int* __restrict__ pull_keys,
                                    int* __restrict__ dest) {
    int j = blockIdx.x * blockDim.x + threadIdx.x;
    if (j >= n) return;
    int key = pull_idx[j];
    int b = key >> BSHIFT;
    int p = atomicAdd(&cur_pull[b * PAD], 1);
    pull_keys[p] = key;
    dest[j] = p;
}

__global__ __launch_bounds__(512)
void match_kernel(const unsigned long long* __restrict__ push_pairs,
                  const int* __restrict__ pull_keys,
                  const int* __restrict__ off_push, const int* __restrict__ cnt_push,
                  const int* __restrict__ off_pull, const int* __restrict__ cnt_pull,
                  const float* __restrict__ x,
                  const float* __restrict__ emb,
                  float* __restrict__ staging) {
    __shared__ unsigned long long tbl[LSLOTS];   // 64KB
    int b = blockIdx.x;
    int np = cnt_push[b * PAD], pb = off_push[b];
    int nl = cnt_pull[b * PAD], lb = off_pull[b];
    for (int t = threadIdx.x; t < LSLOTS; t += 512) tbl[t] = 0ull;
    __syncthreads();
    // build exact last-write-wins hash of this bucket's pushes
    for (int t = threadIdx.x; t < np; t += 512) {
        unsigned long long e = push_pairs[pb + t];
        unsigned key = (unsigned)(e >> 32);
        unsigned s = ((key * 2654435761u) >> 19) & LMASK;
        for (;;) {
            unsigned long long prev = atomicCAS(&tbl[s], 0ull, e);
            if (prev == 0ull) break;                     // claimed
            if ((prev >> 32) == key) {                   // same key
                atomicMax(&tbl[s], e);                   // max over pos
                break;
            }
            s = (s + 1) & LMASK;
        }
    }
    __syncthreads();
    // probe pulls, gather, write bucket-ordered (coalesced)
    for (int t = threadIdx.x; t < nl; t += 512) {
        int key = pull_keys[lb + t];
        unsigned s = (((unsigned)key * 2654435761u) >> 19) & LMASK;
        float v;
        for (;;) {
            unsigned long long cur = tbl[s];
            if (cur == 0ull) { v = emb[key]; break; }            // not pushed
            if ((cur >> 32) == (unsigned)key) { v = x[(unsigned)cur - 1u]; break; }
            s = (s + 1) & LMASK;
        }
        staging[lb + t] = v;
    }
}

__global__ void unpermute_kernel(const int* __restrict__ dest,
                                 const float* __restrict__ staging,
                                 float* __restrict__ out, int n) {
    int j = blockIdx.x * blockDim.x + threadIdx.x;
    if (j < n) out[j] = staging[dest[j]];
}

extern "C" void kernel_launch(void* const* d_in, const int* in_sizes, int n_in,
                              void* d_out, int out_size, void* d_ws, size_t ws_size,
                              hipStream_t stream) {
    const float* emb      = (const float*)d_in[0];
    const float* x        = (const float*)d_in[1];
    const int*   push_idx = (const int*)d_in[2];
    const int*   pull_idx = (const int*)d_in[3];
    float* out = (float*)d_out;

    const int n_push = in_sizes[2];
    const int n_pull = in_sizes[3];

    // ws layout (all 8B-aligned):
    char* p = (char*)d_ws;
    unsigned long long* push_pairs = (unsigned long long*)p;  p += (size_t)n_push * 8;
    int*   pull_keys = (int*)p;                               p += (size_t)n_pull * 4;
    int*   dest      = (int*)p;                               p += (size_t)n_pull * 4;
    float* staging   = (float*)p;                             p += (size_t)n_pull * 4;
    int*   cnt_push  = (int*)p;                               p += NB * PAD * 4;
    int*   cnt_pull  = (int*)p;                               p += NB * PAD * 4;
    int*   cur_push  = (int*)p;                               p += NB * PAD * 4;
    int*   cur_pull  = (int*)p;                               p += NB * PAD * 4;
    int*   off_push  = (int*)p;                               p += NB * 4;
    int*   off_pull  = (int*)p;                               p += NB * 4;

    // zero the two count arrays (contiguous region)
    hipMemsetAsync(cnt_push, 0, (size_t)2 * NB * PAD * 4, stream);

    const int B = 256;
    int n_max = n_push > n_pull ? n_push : n_pull;
    int hist_grid = (n_max + B * HIST_ELEMS - 1) / (B * HIST_ELEMS);
    hist_kernel<<<hist_grid, B, 0, stream>>>(push_idx, pull_idx, n_push, n_pull,
                                             cnt_push, cnt_pull);
    scan_kernel<<<1, NB, 0, stream>>>(cnt_push, cnt_pull, off_push, off_pull,
                                      cur_push, cur_pull);
    scatter_push_kernel<<<(n_push + B - 1) / B, B, 0, stream>>>(push_idx, n_push,
                                                                cur_push, push_pairs);
    scatter_pull_kernel<<<(n_pull + B - 1) / B, B, 0, stream>>>(pull_idx, n_pull,
                                                                cur_pull, pull_keys, dest);
    match_kernel<<<NB, 512, 0, stream>>>(push_pairs, pull_keys,
                                         off_push, cnt_push, off_pull, cnt_pull,
                                         x, emb, staging);
    unpermute_kernel<<<(n_pull + B - 1) / B, B, 0, stream>>>(dest, staging, out, n_pull);
}

// Round 5
// 381.094 us; speedup vs baseline: 2.1895x; 2.1895x over previous
//
#include <hip/hip_runtime.h>
#include <stdint.h>

// ---------------------------------------------------------------------------
// HistoryEmbTable: emb.at[push_idx].set(x) then gather emb[pull_idx].
// Last push (highest i) wins on duplicate push indices.
//
// Structure (round-3, best so far at 342us):
//   1. bitmap (60M bits = 7.5MB) of PULLED keys via atomicOr.
//   2. filtered insert: only pushes whose key is pulled (~258K expected) into
//      a 4MB open-addressed table (2^19 x 8B, lf ~0.49) -> XCD-L2 resident.
//   3. pull: probe table and gather emb[key] in parallel, select.
// Round-5 change: batch 8 elements/thread in every pass. One coalesced
// int4x2 index load, then 8 INDEPENDENT random accesses in flight per thread
// (16 for pull: 8 probes + 8 emb gathers). These passes are random-access
// latency-rate-bound, not BW-bound: more MLP per wave slot is the lever.
// Output written directly in pull order (coalesced float4x2).
//
// Slot (u64) = ((key+1)<<32) | (pos+1); 0 = empty. CAS claims empty slot,
// atomicMax on key-match (high bits equal -> max over pos) = last-write-wins.
// ---------------------------------------------------------------------------

typedef unsigned long long u64;

#define TBL_BITS  19
#define TBL_SLOTS (1u << TBL_BITS)
#define TBL_MASK  (TBL_SLOTS - 1u)
#define BATCH     8

__device__ __forceinline__ unsigned hash_slot(int key) {
    return ((unsigned)key * 2654435761u) >> (32 - TBL_BITS);
}

__device__ __forceinline__ void table_insert(u64* __restrict__ table,
                                             int key, int pos) {
    u64 desired = ((u64)(unsigned)(key + 1) << 32) | (unsigned)(pos + 1);
    unsigned slot = hash_slot(key);
    for (;;) {
        u64 prev = atomicCAS(&table[slot], 0ull, desired);
        if (prev == 0ull) return;                   // claimed empty slot
        if ((prev >> 32) == (unsigned)(key + 1)) {  // key already present
            atomicMax(&table[slot], desired);       // last-write-wins on pos
            return;
        }
        slot = (slot + 1) & TBL_MASK;
    }
}

__global__ void bitmap_build_kernel(const int* __restrict__ pull_idx,
                                    unsigned* __restrict__ bitmap, int n) {
    int i0 = (blockIdx.x * blockDim.x + threadIdx.x) * BATCH;
    if (i0 + BATCH <= n) {
        int4 a = *(const int4*)(pull_idx + i0);
        int4 b = *(const int4*)(pull_idx + i0 + 4);
        int k[BATCH] = {a.x, a.y, a.z, a.w, b.x, b.y, b.z, b.w};
        #pragma unroll
        for (int e = 0; e < BATCH; ++e)
            atomicOr(&bitmap[k[e] >> 5], 1u << (k[e] & 31));
    } else {
        for (int i = i0; i < n; ++i) {
            int key = pull_idx[i];
            atomicOr(&bitmap[key >> 5], 1u << (key & 31));
        }
    }
}

__global__ void filtered_insert_kernel(const int* __restrict__ push_idx,
                                       const unsigned* __restrict__ bitmap,
                                       u64* __restrict__ table, int n) {
    int i0 = (blockIdx.x * blockDim.x + threadIdx.x) * BATCH;
    if (i0 + BATCH <= n) {
        int4 a = *(const int4*)(push_idx + i0);
        int4 b = *(const int4*)(push_idx + i0 + 4);
        int k[BATCH] = {a.x, a.y, a.z, a.w, b.x, b.y, b.z, b.w};
        unsigned w[BATCH];
        #pragma unroll
        for (int e = 0; e < BATCH; ++e) w[e] = bitmap[k[e] >> 5];  // 8 in flight
        #pragma unroll
        for (int e = 0; e < BATCH; ++e)
            if ((w[e] >> (k[e] & 31)) & 1u) table_insert(table, k[e], i0 + e);
    } else {
        for (int i = i0; i < n; ++i) {
            int key = push_idx[i];
            if ((bitmap[key >> 5] >> (key & 31)) & 1u) table_insert(table, key, i);
        }
    }
}

__global__ void pull_kernel(const int* __restrict__ pull_idx,
                            const u64* __restrict__ table,
                            const float* __restrict__ x,
                            const float* __restrict__ emb,
                            float* __restrict__ out, int n) {
    int i0 = (blockIdx.x * blockDim.x + threadIdx.x) * BATCH;
    if (i0 + BATCH <= n) {
        int4 a = *(const int4*)(pull_idx + i0);
        int4 b = *(const int4*)(pull_idx + i0 + 4);
        int k[BATCH] = {a.x, a.y, a.z, a.w, b.x, b.y, b.z, b.w};
        unsigned s[BATCH];
        #pragma unroll
        for (int e = 0; e < BATCH; ++e) s[e] = hash_slot(k[e]);
        u64 t[BATCH];
        #pragma unroll
        for (int e = 0; e < BATCH; ++e) t[e] = table[s[e]];   // 8 probes in flight
        float g[BATCH];
        #pragma unroll
        for (int e = 0; e < BATCH; ++e) g[e] = emb[k[e]];     // 8 gathers in flight
        float r[BATCH];
        #pragma unroll
        for (int e = 0; e < BATCH; ++e) {
            u64 cur = t[e];
            unsigned slot = s[e];
            float v = g[e];
            while (cur != 0ull) {                  // occupied slot
                if ((cur >> 32) == (unsigned)(k[e] + 1)) {
                    v = x[(unsigned)cur - 1u];     // pushed: winner's x
                    break;
                }
                slot = (slot + 1) & TBL_MASK;      // collision: keep probing
                cur = table[slot];
            }
            r[e] = v;
        }
        *(float4*)(out + i0)     = make_float4(r[0], r[1], r[2], r[3]);
        *(float4*)(out + i0 + 4) = make_float4(r[4], r[5], r[6], r[7]);
    } else {
        for (int j = i0; j < n; ++j) {
            int key = pull_idx[j];
            float v = emb[key];
            unsigned slot = hash_slot(key);
            for (;;) {
                u64 cur = table[slot];
                if (cur == 0ull) break;
                if ((cur >> 32) == (unsigned)(key + 1)) { v = x[(unsigned)cur - 1u]; break; }
                slot = (slot + 1) & TBL_MASK;
            }
            out[j] = v;
        }
    }
}

extern "C" void kernel_launch(void* const* d_in, const int* in_sizes, int n_in,
                              void* d_out, int out_size, void* d_ws, size_t ws_size,
                              hipStream_t stream) {
    const float* emb      = (const float*)d_in[0];
    const float* x        = (const float*)d_in[1];
    const int*   push_idx = (const int*)d_in[2];
    const int*   pull_idx = (const int*)d_in[3];
    float* out = (float*)d_out;

    const int num_emb = in_sizes[0];
    const int n_push  = in_sizes[2];
    const int n_pull  = in_sizes[3];

    // ws layout: [bitmap (num_emb bits, 8B-aligned)] [table (TBL_SLOTS u64)]
    const size_t bitmap_words = ((size_t)num_emb + 31) / 32;
    const size_t bitmap_bytes = ((bitmap_words * 4 + 7) / 8) * 8;
    unsigned* bitmap = (unsigned*)d_ws;
    u64* table = (u64*)((char*)d_ws + bitmap_bytes);

    // single contiguous memset over bitmap + table
    hipMemsetAsync(d_ws, 0, bitmap_bytes + (size_t)TBL_SLOTS * 8, stream);

    const int B = 256;
    auto grid_for = [&](int n) { return (n + B * BATCH - 1) / (B * BATCH); };

    bitmap_build_kernel<<<grid_for(n_pull), B, 0, stream>>>(pull_idx, bitmap, n_pull);
    filtered_insert_kernel<<<grid_for(n_push), B, 0, stream>>>(push_idx, bitmap,
                                                               table, n_push);
    pull_kernel<<<grid_for(n_pull), B, 0, stream>>>(pull_idx, table, x, emb,
                                                    out, n_pull);
}